// Round 7
// baseline (57.131 us; speedup 1.0000x reference)
//
#include <hip/hip_runtime.h>

// SpikeEncoder: out[b,h] = ( sum_k count[b,k]*W2[h,k] + S*T*b2[h] ) / B
// R7: gather + fp32->fp16 hi/lo split FUSED into gemm1 (no packed tensors,
// no 36MB round-trip). Reg-stage A(gather)/W1 fp32, cvt in-register,
// ds_write to the swizzled layout; split-fp16 2-term MFMA; LIF in-block.
//
// ws: part[4MB) | cnt[256KB)

#define TSTEPS 10
#define SEQ    64
#define BATCH  64
#define EDIM   1024
#define HDIM   1024
#define KSPLIT 16

typedef unsigned short u16;
typedef __attribute__((ext_vector_type(8))) _Float16 half8;
typedef __attribute__((ext_vector_type(8))) unsigned short ushort8;
typedef __attribute__((ext_vector_type(4))) float  f32x4;

union h16 { _Float16 f; u16 u; };

__device__ __forceinline__ u16 f2h_bits(float x) {
    h16 t; t.f = (_Float16)x; return t.u;       // RNE
}
__device__ __forceinline__ float h2f(u16 b) {
    h16 t; t.u = b; return (float)t.f;
}

// ---- GEMM1 (fused gather+split, fp16 2-term MFMA) + in-block LIF ---------
#define BM 64
#define BN 128
#define BK 32
#define NT (EDIM / BK)
// u16 offsets inside one 16KB buffer:
#define AH 0          // [64][32]
#define AL 2048
#define WH 4096       // [128][32]
#define BUFU 8192     // 16KB in u16 units

__global__ __launch_bounds__(256) void gemm1_lif(
    const int* __restrict__ idx,
    const float* __restrict__ emb,
    const float* __restrict__ W1,
    const float* __restrict__ bias1,
    const float* __restrict__ pthr, const float* __restrict__ pleak,
    float* __restrict__ cnt)
{
    __shared__ float smf[8448];     // 33792B: 2x16KB staging / ct[128][66]
    __shared__ int ridx[64];
    u16*   stage = (u16*)smf;
    float* ct    = smf;

    // bx = bid&7: one W1 slab per XCD stays L2-hot; A rows L3-shared
    const int bid = blockIdx.x;
    const int bx = bid & 7;          // 0..7  (k-slab of W1)
    const int by = bid >> 3;         // 0..63 (= batch b)
    const int col0 = bx * BN;

    const int tid  = threadIdx.x;
    const int wave = tid >> 6, lane = tid & 63;
    const int wn   = wave;           // wave grid 1x4, tile 64x32
    const int lrow = lane & 15, kgrp = lane >> 4;

    // gather indices: GEMM row s of this block = emb[idx[s*64 + by]]
    if (tid < 64) ridx[tid] = idx[tid * 64 + by];
    __syncthreads();

    // reg-staging assignments
    const int ar  = tid >> 2;                 // A row 0..63
    const int aq  = tid & 3;                  // 8-float chunk 0..3
    const int asl = aq ^ ((ar >> 1) & 3);     // swizzled dest slot
    const int wr  = tid >> 1;                 // W row 0..127
    const int wq2 = (tid & 1) * 2;            // first of 2 chunks
    const int wsw = (wr >> 1) & 3;
    const float* wbase = W1 + (size_t)(col0 + wr) * EDIM + wq2 * 8;

    float4 a0, a1, w0, w1, w2, w3;
    auto LOADR = [&](int k0) {
        const float* ap = emb + (size_t)ridx[ar] * EDIM + k0 + aq * 8;
        a0 = *(const float4*)ap;
        a1 = *(const float4*)(ap + 4);
        const float* wp = wbase + k0;
        w0 = *(const float4*)wp;       w1 = *(const float4*)(wp + 4);
        w2 = *(const float4*)(wp + 8); w3 = *(const float4*)(wp + 12);
    };

    auto CVTWRITE = [&](int b) {
        u16* lb = stage + b * BUFU;
        float xa[8] = {a0.x, a0.y, a0.z, a0.w, a1.x, a1.y, a1.z, a1.w};
        ushort8 h, l;
#pragma unroll
        for (int j = 0; j < 8; ++j) {
            u16 hh = f2h_bits(xa[j]);
            h[j] = hh;
            l[j] = f2h_bits((xa[j] - h2f(hh)) * 2048.0f);
        }
        *(ushort8*)(lb + AH + ar * 32 + asl * 8) = h;
        *(ushort8*)(lb + AL + ar * 32 + asl * 8) = l;
        float xw[16] = {w0.x, w0.y, w0.z, w0.w, w1.x, w1.y, w1.z, w1.w,
                        w2.x, w2.y, w2.z, w2.w, w3.x, w3.y, w3.z, w3.w};
        ushort8 p0, p1;
#pragma unroll
        for (int j = 0; j < 8; ++j) {
            p0[j] = f2h_bits(xw[j]);
            p1[j] = f2h_bits(xw[8 + j]);
        }
        *(ushort8*)(lb + WH + wr * 32 + ((wq2    ) ^ wsw) * 8) = p0;
        *(ushort8*)(lb + WH + wr * 32 + ((wq2 + 1) ^ wsw) * 8) = p1;
    };

    f32x4 acc[4][2], acl[4][2];
    const f32x4 zero = {0.f, 0.f, 0.f, 0.f};
#pragma unroll
    for (int m = 0; m < 4; ++m)
#pragma unroll
        for (int n = 0; n < 2; ++n) { acc[m][n] = zero; acl[m][n] = zero; }

    auto COMPUTE = [&](int b) {
        const u16* lb = stage + b * BUFU;
        half8 ah[4], al[4], bh[2];
#pragma unroll
        for (int n = 0; n < 2; ++n) {
            const int c = wn * 32 + n * 16 + lrow;
            const int s = kgrp ^ ((c >> 1) & 3);
            bh[n] = *(const half8*)(lb + WH + c * 32 + s * 8);
        }
#pragma unroll
        for (int m = 0; m < 4; ++m) {
            const int r = m * 16 + lrow;
            const int s = kgrp ^ ((r >> 1) & 3);
            const u16* p = lb + AH + r * 32 + s * 8;
            ah[m] = *(const half8*)p;
            al[m] = *(const half8*)(p + (AL - AH));
        }
#pragma unroll
        for (int m = 0; m < 4; ++m)
#pragma unroll
            for (int n = 0; n < 2; ++n) {
                acc[m][n] = __builtin_amdgcn_mfma_f32_16x16x32_f16(ah[m], bh[n], acc[m][n], 0, 0, 0);
                acl[m][n] = __builtin_amdgcn_mfma_f32_16x16x32_f16(al[m], bh[n], acl[m][n], 0, 0, 0);
            }
    };

    // T14 2-phase: cvt+ds_write(t) | barrier | issue loads(t+1) | MFMA(t) | barrier
    LOADR(0);
#pragma unroll 2
    for (int t = 0; t < NT; ++t) {
        CVTWRITE(t & 1);
        __syncthreads();
        if (t + 1 < NT) LOADR((t + 1) * BK);   // HBM/L2 latency hides under MFMA
        COMPUTE(t & 1);
        __syncthreads();
    }

    // C/D layout: col=lane&15, row=(lane>>4)*4+j.  ct[kcol][s], stride 66.
#pragma unroll
    for (int n = 0; n < 2; ++n) {
        const int kc = wn * 32 + n * 16 + lrow;
#pragma unroll
        for (int m = 0; m < 4; ++m) {
            const int sb = m * 16 + kgrp * 4;
#pragma unroll
            for (int j = 0; j < 4; ++j)
                ct[kc * 66 + sb + j] = acc[m][n][j] + acl[m][n][j] * (1.0f / 2048.0f);
        }
    }
    __syncthreads();

    // LIF recurrence: thread k walks ct[k][s], s=0..63, 10 substeps each
    if (tid < BN) {
        const float thr = pthr[0];
        const float lk  = pleak[0];
        const float b1v = bias1[col0 + tid];
        const float* row = ct + tid * 66;
        float mem1 = 0.f, c = 0.f;
        for (int s = 0; s < SEQ; ++s) {
            const float x = row[s] + b1v;
#pragma unroll
            for (int t = 0; t < TSTEPS; ++t) {
                mem1 = lk * mem1 + x;
                if (mem1 > thr) { c += 1.f; mem1 -= thr; }
            }
        }
        cnt[(size_t)by * HDIM + col0 + tid] = c;
    }
}

// ---- GEMM2 (K-split partials): part[kc][b][h] ----------------------------
__global__ __launch_bounds__(256) void gemm2_partial(
    const float* __restrict__ cnt,
    const float* __restrict__ W2,
    float* __restrict__ part)
{
    __shared__ float As[32][68];
    __shared__ float Bs[32][132];

    const int tid   = threadIdx.x;
    const int col0  = blockIdx.x * 128;
    const int kc    = blockIdx.y;
    const int kbase = kc * 64;

    const int lr = tid >> 3;
    const int lc = (tid & 7) * 4;
    const int tm = (tid >> 4) * 4;
    const int tn = (tid & 15) * 4;

    float acc[4][8];
#pragma unroll
    for (int i = 0; i < 4; ++i)
#pragma unroll
        for (int j = 0; j < 8; ++j) acc[i][j] = 0.f;

    for (int kt = 0; kt < 2; ++kt) {
        const int k0 = kbase + kt * 32;
#pragma unroll
        for (int p = 0; p < 2; ++p) {
            int r = p * 32 + lr;
            float4 v = *(const float4*)(cnt + (size_t)r * HDIM + k0 + lc);
            As[lc + 0][r] = v.x; As[lc + 1][r] = v.y;
            As[lc + 2][r] = v.z; As[lc + 3][r] = v.w;
        }
#pragma unroll
        for (int p = 0; p < 4; ++p) {
            int r = p * 32 + lr;
            float4 v = *(const float4*)(W2 + (size_t)(col0 + r) * HDIM + k0 + lc);
            Bs[lc + 0][r] = v.x; Bs[lc + 1][r] = v.y;
            Bs[lc + 2][r] = v.z; Bs[lc + 3][r] = v.w;
        }
        __syncthreads();
#pragma unroll 8
        for (int k = 0; k < 32; ++k) {
            float4 a   = *(const float4*)&As[k][tm];
            float4 bb0 = *(const float4*)&Bs[k][tn];
            float4 bb1 = *(const float4*)&Bs[k][tn + 64];
            float av[4] = {a.x, a.y, a.z, a.w};
            float bv[8] = {bb0.x, bb0.y, bb0.z, bb0.w, bb1.x, bb1.y, bb1.z, bb1.w};
#pragma unroll
            for (int i = 0; i < 4; ++i)
#pragma unroll
                for (int j = 0; j < 8; ++j)
                    acc[i][j] += av[i] * bv[j];
        }
        __syncthreads();
    }

#pragma unroll
    for (int i = 0; i < 4; ++i) {
        float* prow = part + (size_t)kc * (BATCH * HDIM) + (size_t)(tm + i) * HDIM + col0;
        float4 o0, o1;
        o0.x = acc[i][0]; o0.y = acc[i][1]; o0.z = acc[i][2]; o0.w = acc[i][3];
        o1.x = acc[i][4]; o1.y = acc[i][5]; o1.z = acc[i][6]; o1.w = acc[i][7];
        *(float4*)(prow + tn)      = o0;
        *(float4*)(prow + tn + 64) = o1;
    }
}

// ---- final reduce: out = (sum_kc part + 640*b2) / 64 ----------------------
__global__ __launch_bounds__(256) void reduce_out(
    const float* __restrict__ part,
    const float* __restrict__ b2,
    float* __restrict__ out)
{
    const int i = blockIdx.x * 256 + threadIdx.x;
    float s = 0.f;
#pragma unroll
    for (int kc = 0; kc < KSPLIT; ++kc)
        s += part[(size_t)kc * (BATCH * HDIM) + i];
    const int h = i & (HDIM - 1);
    out[i] = (s + (float)(SEQ * TSTEPS) * b2[h]) * (1.0f / (float)BATCH);
}

extern "C" void kernel_launch(void* const* d_in, const int* in_sizes, int n_in,
                              void* d_out, int out_size, void* d_ws, size_t ws_size,
                              hipStream_t stream)
{
    (void)in_sizes; (void)n_in; (void)out_size; (void)ws_size;

    const int*   idx  = (const int*)d_in[0];
    const float* emb  = (const float*)d_in[1];
    const float* W1   = (const float*)d_in[2];
    const float* b1   = (const float*)d_in[3];
    const float* W2   = (const float*)d_in[4];
    const float* b2   = (const float*)d_in[5];
    const float* thr  = (const float*)d_in[6];
    const float* leak = (const float*)d_in[7];
    float* out = (float*)d_out;

    char* ws = (char*)d_ws;
    float* part = (float*)ws;                                       // 4 MB
    float* cnt  = (float*)(ws + (size_t)KSPLIT * BATCH * HDIM * 4); // 256 KB

    gemm1_lif<<<dim3(BATCH * (HDIM / BN)), 256, 0, stream>>>(
        idx, emb, W1, b1, thr, leak, cnt);

    gemm2_partial<<<dim3(HDIM / 128, KSPLIT), 256, 0, stream>>>(cnt, W2, part);

    reduce_out<<<dim3((BATCH * HDIM) / 256), 256, 0, stream>>>(part, b2, out);
}